// Round 4
// baseline (120.550 us; speedup 1.0000x reference)
//
#include <hip/hip_runtime.h>
#include <math.h>

#define NB 1024
#define N 256
#define ROWS 4
#define EPS 1e-6f
#define SQRT_EPS 1e-3f   // sqrt(1e-6)

__device__ __forceinline__ float fast_rcp(float x) {
    return __builtin_amdgcn_rcpf(x);      // v_rcp_f32
}

__device__ __forceinline__ float sigmoidf(float x) {
    return fast_rcp(1.0f + __expf(-x));
}

__device__ __forceinline__ float fast_tanh(float x) {
    float ax = fabsf(x);
    float e  = __expf(2.0f * ax);
    float t  = 1.0f - 2.0f * fast_rcp(e + 1.0f);   // e=inf -> t=1
    return copysignf(t, x);
}

__device__ __forceinline__ float dot4(float4 a, float4 b) {
    return a.x * b.x + a.y * b.y + a.z * b.z + a.w * b.w;
}

// grid 256, block 512. sub = tid>>8 selects k-half [sub*128, sub*128+128).
__global__ __launch_bounds__(512) void mlp_kernel(
    const float* __restrict__ x,
    const float* __restrict__ Wd1, const float* __restrict__ bd1,
    const float* __restrict__ Wd2, const float* __restrict__ bd2,
    const float* __restrict__ Wu1, const float* __restrict__ bu1,
    const float* __restrict__ Wu2, const float* __restrict__ bu2,
    const float* __restrict__ Wm1, const float* __restrict__ bm1,
    const float* __restrict__ Wm2, const float* __restrict__ bm2,
    const float* __restrict__ v,
    float* __restrict__ out_mean, float* __restrict__ out_z,
    float* __restrict__ ws_a, float* __restrict__ ws_tp, float* __restrict__ ws_s)
{
    __shared__ float xs[ROWS][N];        // 4 KB
    __shared__ float h[3][ROWS][N];      // 12 KB (d,u,m) hidden then final
    __shared__ float ps[N][13];          // 13 KB partial sums (pad 13: conflict-free)
    __shared__ float red1[8][6];
    __shared__ float red2[8][2];

    const int tid = threadIdx.x;
    const int t   = tid & 255;           // neuron
    const int sub = tid >> 8;            // k-half
    const int b0  = blockIdx.x * ROWS;

    // ---- load x rows (coalesced float4) ----
    if (tid < 256)
        ((float4*)xs)[tid] = ((const float4*)(x + (size_t)b0 * N))[tid];

    // this thread owns batch rows sub*2+0, sub*2+1 in the epilogue
    float vv[2];
    #pragma unroll
    for (int q = 0; q < 2; ++q)
        vv[q] = v[(size_t)(b0 + sub * 2 + q) * N + t];

    __syncthreads();

    const int koff = sub * (N / 2);      // 128-float offset into k

    // ---- layer 1 (split-K partial) ----
    float acc[12];
    #pragma unroll
    for (int i = 0; i < 12; ++i) acc[i] = 0.f;
    {
        const float4* wd = (const float4*)(Wd1 + (size_t)t * N + koff);
        const float4* wu = (const float4*)(Wu1 + (size_t)t * N + koff);
        const float4* wm = (const float4*)(Wm1 + (size_t)t * N + koff);
        #pragma unroll 4
        for (int k4 = 0; k4 < 32; ++k4) {
            float4 w1 = wd[k4];
            float4 w2 = wu[k4];
            float4 w3 = wm[k4];
            #pragma unroll
            for (int r = 0; r < ROWS; ++r) {
                float4 xv = ((const float4*)&xs[r][koff])[k4];
                acc[r]     += dot4(w1, xv);
                acc[4 + r] += dot4(w2, xv);
                acc[8 + r] += dot4(w3, xv);
            }
        }
    }
    if (sub == 1) {
        #pragma unroll
        for (int i = 0; i < 12; ++i) ps[t][i] = acc[i];
    }
    __syncthreads();
    if (sub == 0) {
        float b1 = bd1[t], b2 = bu1[t], b3 = bm1[t];
        #pragma unroll
        for (int r = 0; r < ROWS; ++r) {
            h[0][r][t] = sigmoidf(acc[r]     + ps[t][r]     + b1);
            h[1][r][t] = sigmoidf(acc[4 + r] + ps[t][4 + r] + b2);
            h[2][r][t] = fast_tanh(acc[8 + r] + ps[t][8 + r] + b3);
        }
    }
    __syncthreads();

    // ---- layer 2 (split-K partial) ----
    #pragma unroll
    for (int i = 0; i < 12; ++i) acc[i] = 0.f;
    {
        const float4* wd = (const float4*)(Wd2 + (size_t)t * N + koff);
        const float4* wu = (const float4*)(Wu2 + (size_t)t * N + koff);
        const float4* wm = (const float4*)(Wm2 + (size_t)t * N + koff);
        #pragma unroll 4
        for (int k4 = 0; k4 < 32; ++k4) {
            float4 w1 = wd[k4];
            float4 w2 = wu[k4];
            float4 w3 = wm[k4];
            #pragma unroll
            for (int r = 0; r < ROWS; ++r) {
                float4 hdv = ((const float4*)&h[0][r][koff])[k4];
                float4 huv = ((const float4*)&h[1][r][koff])[k4];
                float4 hmv = ((const float4*)&h[2][r][koff])[k4];
                acc[r]     += dot4(w1, hdv);
                acc[4 + r] += dot4(w2, huv);
                acc[8 + r] += dot4(w3, hmv);
            }
        }
    }
    __syncthreads();                      // all h reads done before overwrite
    if (sub == 1) {
        #pragma unroll
        for (int i = 0; i < 12; ++i) ps[t][i] = acc[i];
    }
    __syncthreads();
    if (sub == 0) {
        float b1 = bd2[t], b2 = bu2[t], b3 = bm2[t];
        #pragma unroll
        for (int r = 0; r < ROWS; ++r) {
            h[0][r][t] = sigmoidf(acc[r]     + ps[t][r]     + b1);   // d
            h[1][r][t] = sigmoidf(acc[4 + r] + ps[t][4 + r] + b2);   // u
            h[2][r][t] = fast_tanh(acc[8 + r] + ps[t][8 + r] + b3);  // m
        }
    }
    __syncthreads();

    // ---- epilogue: this thread owns rows q = sub*2 + {0,1} ----
    const int lane = tid & 63;
    const int wid  = tid >> 6;            // 0..7; waves 0-3 are sub0, 4-7 sub1

    float d_[2], u_[2], m_[2], inv_d[2];
    float vals[6];
    #pragma unroll
    for (int q = 0; q < 2; ++q) {
        const int r = sub * 2 + q;
        d_[q] = h[0][r][t];
        u_[q] = h[1][r][t];
        m_[q] = h[2][r][t];
        inv_d[q] = fast_rcp(d_[q]);
        vals[q * 3 + 0] = u_[q];
        vals[q * 3 + 1] = u_[q] * u_[q] * inv_d[q];
        vals[q * 3 + 2] = vv[q];
    }
    #pragma unroll
    for (int k = 0; k < 6; ++k) {
        #pragma unroll
        for (int off = 32; off > 0; off >>= 1)
            vals[k] += __shfl_down(vals[k], off, 64);
    }
    if (lane == 0) {
        #pragma unroll
        for (int k = 0; k < 6; ++k) red1[wid][k] = vals[k];
    }
    __syncthreads();

    float a_[2], s_[2], tp_[2], Sv_[2];
    float vals2[2];
    #pragma unroll
    for (int q = 0; q < 2; ++q) {
        const int w0 = sub * 4;
        float Su = red1[w0][q*3+0] + red1[w0+1][q*3+0] + red1[w0+2][q*3+0] + red1[w0+3][q*3+0];
        float qq = red1[w0][q*3+1] + red1[w0+1][q*3+1] + red1[w0+2][q*3+1] + red1[w0+3][q*3+1];
        Sv_[q]   = red1[w0][q*3+2] + red1[w0+1][q*3+2] + red1[w0+2][q*3+2] + red1[w0+3][q*3+2];
        float utDu  = qq + EPS * Su * Su;
        float sqeta = rsqrtf(1.0f + utDu);
        float right = (1.0f - sqeta) / utDu;
        float a  = sqrtf(inv_d[q] + EPS);
        float s  = u_[q] * a + SQRT_EPS * (Su - u_[q]);
        float tp = right * (u_[q] * inv_d[q] + EPS * Su);
        a_[q] = a; s_[q] = s; tp_[q] = tp;
        vals2[q] = s * vv[q];
    }
    #pragma unroll
    for (int q = 0; q < 2; ++q) {
        #pragma unroll
        for (int off = 32; off > 0; off >>= 1)
            vals2[q] += __shfl_down(vals2[q], off, 64);
    }
    if (lane == 0) {
        #pragma unroll
        for (int q = 0; q < 2; ++q) red2[wid][q] = vals2[q];
    }
    __syncthreads();

    #pragma unroll
    for (int q = 0; q < 2; ++q) {
        const int r = sub * 2 + q;
        const int w0 = sub * 4;
        const size_t row = (size_t)(b0 + r) * N + t;
        float sv = red2[w0][q] + red2[w0+1][q] + red2[w0+2][q] + red2[w0+3][q];
        float z  = SQRT_EPS * Sv_[q] + (a_[q] - SQRT_EPS) * vv[q] - tp_[q] * sv + m_[q];
        out_mean[row] = m_[q];
        out_z[row]    = z;
        ws_a[row]     = a_[q];
        ws_tp[row]    = tp_[q];
        ws_s[row]     = s_[q];
    }
}

// R[b,i,j] = SQRT_EPS + (i==j)*(a_i - SQRT_EPS) - tp_i * s_j
__global__ __launch_bounds__(256) void r_kernel(
    const float* __restrict__ ws_a, const float* __restrict__ ws_tp,
    const float* __restrict__ ws_s, float* __restrict__ R)
{
    __shared__ float s_lds[N];
    __shared__ float a_lds[64];
    __shared__ float tp_lds[64];

    const int tid   = threadIdx.x;
    const int b     = blockIdx.x >> 2;
    const int chunk = blockIdx.x & 3;
    const int ibase = chunk * 64;

    s_lds[tid] = ws_s[(size_t)b * N + tid];
    if (tid < 64) {
        a_lds[tid]  = ws_a[(size_t)b * N + ibase + tid];
        tp_lds[tid] = ws_tp[(size_t)b * N + ibase + tid];
    }
    __syncthreads();

    const int j4 = tid & 63;      // which float4 along j
    const int il = tid >> 6;      // row within group of 4
    const float4 sv = ((const float4*)s_lds)[j4];
    float4* Rb = (float4*)(R + (size_t)b * N * N);
    const int jb = j4 * 4;

    #pragma unroll
    for (int it = 0; it < 16; ++it) {
        const int i_loc = it * 4 + il;
        const int i     = ibase + i_loc;
        const float a   = a_lds[i_loc];
        const float tp  = tp_lds[i_loc];
        float4 o;
        o.x = SQRT_EPS - tp * sv.x;
        o.y = SQRT_EPS - tp * sv.y;
        o.z = SQRT_EPS - tp * sv.z;
        o.w = SQRT_EPS - tp * sv.w;
        if (i >= jb && i < jb + 4) {
            const float add = a - SQRT_EPS;
            if      (i == jb)     o.x += add;
            else if (i == jb + 1) o.y += add;
            else if (i == jb + 2) o.z += add;
            else                  o.w += add;
        }
        Rb[(size_t)i * 64 + j4] = o;
    }
}

extern "C" void kernel_launch(void* const* d_in, const int* in_sizes, int n_in,
                              void* d_out, int out_size, void* d_ws, size_t ws_size,
                              hipStream_t stream) {
    const float* x   = (const float*)d_in[0];
    const float* Wd1 = (const float*)d_in[1];
    const float* bd1 = (const float*)d_in[2];
    const float* Wd2 = (const float*)d_in[3];
    const float* bd2 = (const float*)d_in[4];
    const float* Wu1 = (const float*)d_in[5];
    const float* bu1 = (const float*)d_in[6];
    const float* Wu2 = (const float*)d_in[7];
    const float* bu2 = (const float*)d_in[8];
    const float* Wm1 = (const float*)d_in[9];
    const float* bm1 = (const float*)d_in[10];
    const float* Wm2 = (const float*)d_in[11];
    const float* bm2 = (const float*)d_in[12];
    const float* v   = (const float*)d_in[13];

    float* out      = (float*)d_out;
    float* out_mean = out;                                   // [1024,256]
    float* R        = out + (size_t)NB * N;                  // [1024,256,256]
    float* out_z    = R + (size_t)NB * N * N;                // [1024,256]

    float* wsf   = (float*)d_ws;
    float* ws_a  = wsf;                    // [1024,256]
    float* ws_tp = wsf + (size_t)NB * N;   // [1024,256]
    float* ws_s  = wsf + (size_t)2 * NB * N;

    mlp_kernel<<<NB / ROWS, 512, 0, stream>>>(
        x, Wd1, bd1, Wd2, bd2, Wu1, bu1, Wu2, bu2, Wm1, bm1, Wm2, bm2, v,
        out_mean, out_z, ws_a, ws_tp, ws_s);

    r_kernel<<<NB * 4, 256, 0, stream>>>(ws_a, ws_tp, ws_s, R);
}